// Round 1
// baseline (775.779 us; speedup 1.0000x reference)
//
#include <hip/hip_runtime.h>
#include <math.h>

// Problem constants (fixed by reference): B=64, N=512, D=64, H=4, C=64, L=3
// Workspace layout (floats), ws >= 256 MB:
//   xbuf [0 .. 2097152)         : layer activations x (8 MB)
//   hT   [2097152 .. 10485760)  : h TRANSPOSED [head][c][b*512+n] (32 MB)
//   meta [10485760 .. 11534336) : prep metadata + s/d dots (4 MB)
//   bar  [12000000 .. +16 ints) : one-shot grid-barrier counters (memset to 0 per iter)
// History: R13 wave-shfl segs scans (295->266). R14 (triple change) failed.
// R16 cooperative mega-kernel failed SILENTLY at exact-capacity grid.
// R17 (this): persistent mega-kernel retry with the trap removed:
//   - grid G from hipOccupancyMaxActiveBlocksPerMultiprocessor (co-residency
//     guaranteed by construction), capped at 1024, grid-stride everywhere
//   - 9 ONE-SHOT barrier counters (no generation/reset races), zeroed by a
//     captured hipMemsetAsync (ws is poisoned every iter)
//   - __threadfence + agent-scope acq/rel atomics for cross-XCD visibility
// Phase bodies are verbatim ports of the proven R15 kernels (266 us).

using short8  = __attribute__((ext_vector_type(8))) short;
using floatx4 = __attribute__((ext_vector_type(4))) float;

__device__ inline unsigned short f2bf(float f) {
    union { float f; unsigned u; } v; v.f = f;
    unsigned u = v.u + 0x7FFFu + ((v.u >> 16) & 1u);   // round-to-nearest-even
    return (unsigned short)(u >> 16);
}
__device__ inline float bf2f(unsigned short s) {
    union { float f; unsigned u; } v; v.u = ((unsigned)s) << 16;
    return v.f;
}

#define APW 516

// Per-phase shared memory, unioned (max ~24.8 KB -> 6 blocks/CU LDS-wise).
struct LinS {
    unsigned short WH[64 * 72], WL[64 * 72];
    unsigned short XH[16 * 72], XL[16 * 72];
    float sredS[4][16], sredD[4][16];
};
struct PrepS {
    float s_val[512];
    int   s_idxE[512];
    float z1suf[513], z2pre[513];
    float wred[8];
};
struct AggS {
    float A1[4 * APW], A2[4 * APW];
    float segs1[4 * 65], segs2[4 * 65];
    float tot[4];
    int   kA[512];
    float aZs[512], bZs[512];
};
struct RoS { float red[4][64]; float pooled[64]; };
union __align__(16) SMemU { LinS lin; PrepS prep; AggS agg; RoS ro; };

// One-shot grid barrier: every block adds once, spins until all arrived.
// Counters are pre-zeroed by hipMemsetAsync each iteration. Release-RMW
// (after __threadfence) publishes prior global writes; acquire-load pulls
// them in (agent scope handles per-XCD L2 non-coherence).
__device__ inline void gridbar(int* cnt, int nblk) {
    __syncthreads();
    if (threadIdx.x == 0) {
        __threadfence();
        __hip_atomic_fetch_add(cnt, 1, __ATOMIC_ACQ_REL, __HIP_MEMORY_SCOPE_AGENT);
        while (__hip_atomic_load(cnt, __ATOMIC_ACQUIRE, __HIP_MEMORY_SCOPE_AGENT) < nblk)
            __builtin_amdgcn_s_sleep(2);
    }
    __syncthreads();
}

__global__ __launch_bounds__(256, 4) void mega_kernel(
        const float* __restrict__ emb,
        const float* __restrict__ lin_w_all,
        const float* __restrict__ att_src_all,
        const float* __restrict__ att_dst_all,
        const float* __restrict__ conv_b_all,
        const float* __restrict__ rw,
        const float* __restrict__ rbv,
        float* __restrict__ out,
        float* __restrict__ ws) {
    __shared__ SMemU sm;

    float* xbuf = ws;                    // 8 MB
    float* hT   = ws + 2097152;          // 32 MB, [head][c][b*512+n]
    float* meta = ws + 10485760;         // 4 MB
    int*   g_sidx = (int*)meta;
    float* g_E1   = meta + 131072;
    float* g_E2   = meta + 262144;
    float* g_aZ   = meta + 393216;
    float* g_bZ   = meta + 524288;
    int*   g_k    = (int*)(meta + 655360);
    float* g_s    = meta + 786432;
    float* g_d    = meta + 917504;
    int*   bar    = (int*)(ws + 12000000);

    const int t = threadIdx.x;
    const int G = gridDim.x;

    for (int l = 0; l < 3; ++l) {
        const float* xin     = (l == 0) ? emb : xbuf;
        const float* W       = lin_w_all + (size_t)l * 16384;
        const float* att_src = att_src_all + l * 256;
        const float* att_dst = att_dst_all + l * 256;
        const float* bias    = conv_b_all + l * 64;

        // ------------------------------------------------------------------
        // Phase A: lin (2048 virtual blocks) — MFMA split-bf16, W staged per vb
        // ------------------------------------------------------------------
        for (int vb = blockIdx.x; vb < 2048; vb += G) {
            const int ct = vb >> 9;       // head 0..3
            const int rb = vb & 511;      // row-block (4 rt tiles)
            const int c0 = ct * 64;
            __syncthreads();              // union safety across vb iterations

#pragma unroll
            for (int q = 0; q < 4; ++q) {
                int f = q * 256 + t;
                int wrow = f >> 4, d4 = f & 15;
                float4 v = *(const float4*)(W + (size_t)(c0 + wrow) * 64 + d4 * 4);
                unsigned short h0 = f2bf(v.x), h1 = f2bf(v.y), h2 = f2bf(v.z), h3 = f2bf(v.w);
                ushort4 hi = make_ushort4(h0, h1, h2, h3);
                ushort4 lo = make_ushort4(f2bf(v.x - bf2f(h0)), f2bf(v.y - bf2f(h1)),
                                          f2bf(v.z - bf2f(h2)), f2bf(v.w - bf2f(h3)));
                *(ushort4*)&sm.lin.WH[wrow * 72 + d4 * 4] = hi;
                *(ushort4*)&sm.lin.WL[wrow * 72 + d4 * 4] = lo;
            }
            __syncthreads();

            const int lane = t & 63, wv = t >> 6;
            const int mrow = lane & 15, quad = lane >> 4;
            const int c = wv * 16 + mrow;

            short8 bh[2], bl[2];
#pragma unroll
            for (int kk = 0; kk < 2; ++kk) {
                int ko = kk * 32 + quad * 8;
                bh[kk] = *(const short8*)&sm.lin.WH[(wv * 16 + mrow) * 72 + ko];
                bl[kk] = *(const short8*)&sm.lin.WL[(wv * 16 + mrow) * 72 + ko];
            }
            const float as_c = att_src[c0 + c];
            const float ad_c = att_dst[c0 + c];

#pragma unroll 1
            for (int tt = 0; tt < 4; ++tt) {
                const int rt = rb * 4 + tt;
                const int r0 = rt * 16;
                __syncthreads();

                {
                    int row = t >> 4, d4 = t & 15;
                    float4 v = *(const float4*)(xin + (size_t)(r0 + row) * 64 + d4 * 4);
                    unsigned short h0 = f2bf(v.x), h1 = f2bf(v.y), h2 = f2bf(v.z), h3 = f2bf(v.w);
                    ushort4 hi = make_ushort4(h0, h1, h2, h3);
                    ushort4 lo = make_ushort4(f2bf(v.x - bf2f(h0)), f2bf(v.y - bf2f(h1)),
                                              f2bf(v.z - bf2f(h2)), f2bf(v.w - bf2f(h3)));
                    *(ushort4*)&sm.lin.XH[row * 72 + d4 * 4] = hi;
                    *(ushort4*)&sm.lin.XL[row * 72 + d4 * 4] = lo;
                }
                __syncthreads();

                short8 ah[2], al[2];
#pragma unroll
                for (int kk = 0; kk < 2; ++kk) {
                    int ko = kk * 32 + quad * 8;
                    ah[kk] = *(const short8*)&sm.lin.XH[mrow * 72 + ko];
                    al[kk] = *(const short8*)&sm.lin.XL[mrow * 72 + ko];
                }

                floatx4 acc = {0.f, 0.f, 0.f, 0.f};
                acc = __builtin_amdgcn_mfma_f32_16x16x32_bf16(ah[0], bh[0], acc, 0, 0, 0);
                acc = __builtin_amdgcn_mfma_f32_16x16x32_bf16(ah[1], bh[1], acc, 0, 0, 0);
                acc = __builtin_amdgcn_mfma_f32_16x16x32_bf16(ah[0], bl[0], acc, 0, 0, 0);
                acc = __builtin_amdgcn_mfma_f32_16x16x32_bf16(ah[1], bl[1], acc, 0, 0, 0);
                acc = __builtin_amdgcn_mfma_f32_16x16x32_bf16(al[0], bh[0], acc, 0, 0, 0);
                acc = __builtin_amdgcn_mfma_f32_16x16x32_bf16(al[1], bh[1], acc, 0, 0, 0);

                *(float4*)&hT[(size_t)(ct * 64 + c) * 32768 + r0 + quad * 4] =
                    make_float4(acc[0], acc[1], acc[2], acc[3]);

                float ps[4], pd[4];
#pragma unroll
                for (int reg = 0; reg < 4; ++reg) { ps[reg] = acc[reg] * as_c; pd[reg] = acc[reg] * ad_c; }
#pragma unroll
                for (int m = 1; m <= 8; m <<= 1) {
#pragma unroll
                    for (int reg = 0; reg < 4; ++reg) {
                        ps[reg] += __shfl_xor(ps[reg], m, 64);
                        pd[reg] += __shfl_xor(pd[reg], m, 64);
                    }
                }
                if (mrow < 4) {
                    sm.lin.sredS[wv][quad * 4 + mrow] = ps[mrow];
                    sm.lin.sredD[wv][quad * 4 + mrow] = pd[mrow];
                }
                __syncthreads();
                if (t < 16) {
                    float sS = sm.lin.sredS[0][t] + sm.lin.sredS[1][t] + sm.lin.sredS[2][t] + sm.lin.sredS[3][t];
                    float sD = sm.lin.sredD[0][t] + sm.lin.sredD[1][t] + sm.lin.sredD[2][t] + sm.lin.sredD[3][t];
                    int gn = r0 + t;
                    int bh2 = (gn >> 9) * 4 + ct;
                    int n  = gn & 511;
                    g_s[bh2 * 512 + n] = sS;
                    g_d[bh2 * 512 + n] = sD;
                }
            }
        }
        gridbar(bar + 3 * l + 0, G);

        // ------------------------------------------------------------------
        // Phase B: attn_prep (256 virtual blocks) — bitonic sort + wave scans
        // ------------------------------------------------------------------
        for (int vb = blockIdx.x; vb < 256; vb += G) {
            const int bh = vb;
            const int lane = t & 63;
            const int wid = t >> 6;
            __syncthreads();              // union safety

            float dreg[2];
            for (int rr = 0; rr < 2; ++rr) {
                int j = t + rr * 256;
                sm.prep.s_val[j] = g_s[bh * 512 + j];
                dreg[rr] = g_d[bh * 512 + j];
            }
            __syncthreads();

            float v0 = sm.prep.s_val[2 * t], v1 = sm.prep.s_val[2 * t + 1];
            int id0 = 2 * t, id1 = 2 * t + 1;
            for (int k = 2; k <= 512; k <<= 1) {
                for (int j = k >> 1; j >= 1; j >>= 1) {
                    bool asc = ((t & (k >> 1)) == 0);
                    if (j == 1) {
                        bool sw = asc ? (v0 > v1) : (v0 < v1);
                        if (sw) { float tv = v0; v0 = v1; v1 = tv; int ti = id0; id0 = id1; id1 = ti; }
                    } else if (j <= 64) {
                        int m = j >> 1;
                        float w0 = __shfl_xor(v0, m, 64);
                        int  wi0 = __shfl_xor(id0, m, 64);
                        float w1 = __shfl_xor(v1, m, 64);
                        int  wi1 = __shfl_xor(id1, m, 64);
                        bool low = ((t & m) == 0);
                        bool wantmin = (low == asc);
                        if (wantmin ? (w0 < v0) : (w0 > v0)) { v0 = w0; id0 = wi0; }
                        if (wantmin ? (w1 < v1) : (w1 > v1)) { v1 = w1; id1 = wi1; }
                    } else {
                        int m = j >> 1;
                        sm.prep.s_val[2 * t] = v0; sm.prep.s_val[2 * t + 1] = v1;
                        sm.prep.s_idxE[2 * t] = id0; sm.prep.s_idxE[2 * t + 1] = id1;
                        __syncthreads();
                        int tp = t ^ m;
                        float w0 = sm.prep.s_val[2 * tp], w1 = sm.prep.s_val[2 * tp + 1];
                        int wi0 = sm.prep.s_idxE[2 * tp], wi1 = sm.prep.s_idxE[2 * tp + 1];
                        bool low = ((t & m) == 0);
                        bool wantmin = (low == asc);
                        if (wantmin ? (w0 < v0) : (w0 > v0)) { v0 = w0; id0 = wi0; }
                        if (wantmin ? (w1 < v1) : (w1 > v1)) { v1 = w1; id1 = wi1; }
                        __syncthreads();
                    }
                }
            }

            sm.prep.s_val[2 * t] = v0; sm.prep.s_val[2 * t + 1] = v1;
            __syncthreads();
            const float M = sm.prep.s_val[511];
            float e1_0 = __expf(v0 - M), e1_1 = __expf(v1 - M);
            float e2_0 = __expf(0.2f * (v0 - M)), e2_1 = __expf(0.2f * (v1 - M));
            *(float2*)(g_E1 + bh * 512 + 2 * t) = make_float2(e1_0, e1_1);
            *(float2*)(g_E2 + bh * 512 + 2 * t) = make_float2(e2_0, e2_1);
            *(int2*)(g_sidx + bh * 512 + 2 * t) = make_int2(id0, id1);

            float S1 = e1_0 + e1_1, S2 = e2_0 + e2_1;
            float i1 = S1, i2 = S2;
            for (int off = 1; off < 64; off <<= 1) {
                float u1 = __shfl_up(i1, off, 64);
                float u2 = __shfl_up(i2, off, 64);
                if (lane >= off) { i1 += u1; i2 += u2; }
            }
            if (lane == 63) { sm.prep.wred[wid] = i1; sm.prep.wred[4 + wid] = i2; }
            __syncthreads();
            float off1 = 0.f, off2 = 0.f;
            for (int w = 0; w < wid; ++w) { off1 += sm.prep.wred[w]; off2 += sm.prep.wred[4 + w]; }
            const float T1 = sm.prep.wred[0] + sm.prep.wred[1] + sm.prep.wred[2] + sm.prep.wred[3];
            const float T2 = sm.prep.wred[4] + sm.prep.wred[5] + sm.prep.wred[6] + sm.prep.wred[7];
            float pre1 = off1 + i1 - S1;
            float pre2 = off2 + i2 - S2;
            sm.prep.z1suf[2 * t] = T1 - pre1;
            sm.prep.z1suf[2 * t + 1] = T1 - pre1 - e1_0;
            sm.prep.z2pre[2 * t] = pre2;
            sm.prep.z2pre[2 * t + 1] = pre2 + e2_0;
            if (t == 0) { sm.prep.z1suf[512] = 0.f; sm.prep.z2pre[512] = T2; }
            __syncthreads();

            for (int rr = 0; rr < 2; ++rr) {
                int i = t + rr * 256;
                float d = dreg[rr];
                int lo = 0, hi = 512;
                while (lo < hi) {
                    int mid = (lo + hi) >> 1;
                    if (d + sm.prep.s_val[mid] >= 0.f) hi = mid; else lo = mid + 1;
                }
                int k = lo;
                float g = d + M;
                float Gv = (g >= 0.f) ? g : 0.2f * g;
                float al = __expf(g - Gv);
                float be = __expf(0.2f * g - Gv);
                float Z = al * sm.prep.z1suf[k] + be * sm.prep.z2pre[k];
                float inv = 1.0f / Z;
                g_aZ[bh * 512 + i] = al * inv;
                g_bZ[bh * 512 + i] = be * inv;
                g_k[bh * 512 + i]  = k;
            }
        }
        gridbar(bar + 3 * l + 1, G);

        // ------------------------------------------------------------------
        // Phase C: attn_agg_fin (1024 virtual blocks) — merged suffix+prefix,
        // wave-owned shfl segs scans, fused bias+relu+head-mean x output
        // ------------------------------------------------------------------
        for (int vb = blockIdx.x; vb < 1024; vb += G) {
            const int b  = vb & 63;
            const int cg = vb >> 6;        // 0..15
            const int c0 = cg * 4;
            const int lane = t & 63, wvw = t >> 6;
            const int cl = t & 3, ibase = t >> 2;  // cl: channel, ibase: seg 0..63

            float acc[8];
#pragma unroll
            for (int p = 0; p < 8; ++p) acc[p] = 0.f;

#pragma unroll 1
            for (int head = 0; head < 4; ++head) {
                const int bh = b * 4 + head;
                const float* hTb = hT + (size_t)(head * 64 + c0) * 32768 + b * 512;
                __syncthreads();   // prev head's (or prev phase's) reads done

                for (int rr = 0; rr < 2; ++rr) {
                    int r = t + rr * 256;
                    int j = g_sidx[bh * 512 + r];
                    float e1 = g_E1[bh * 512 + r];
                    float e2 = g_E2[bh * 512 + r];
                    sm.agg.kA[r]  = g_k[bh * 512 + r];
                    sm.agg.aZs[r] = g_aZ[bh * 512 + r];
                    sm.agg.bZs[r] = g_bZ[bh * 512 + r];
#pragma unroll
                    for (int c = 0; c < 4; ++c) {
                        float hvv = hTb[c * 32768 + j];
                        sm.agg.A1[c * APW + r] = e1 * hvv;
                        sm.agg.A2[c * APW + r] = e2 * hvv;
                    }
                }
                __syncthreads();

                float v1[8], v2[8];
                {
                    float* b1 = sm.agg.A1 + cl * APW + ibase * 8;
                    float* b2 = sm.agg.A2 + cl * APW + ibase * 8;
#pragma unroll
                    for (int q4 = 0; q4 < 2; ++q4) {
                        float4 a = *(const float4*)(b1 + q4 * 4);
                        v1[q4 * 4] = a.x; v1[q4 * 4 + 1] = a.y; v1[q4 * 4 + 2] = a.z; v1[q4 * 4 + 3] = a.w;
                        float4 c2 = *(const float4*)(b2 + q4 * 4);
                        v2[q4 * 4] = c2.x; v2[q4 * 4 + 1] = c2.y; v2[q4 * 4 + 2] = c2.z; v2[q4 * 4 + 3] = c2.w;
                    }
                    float s1 = 0.f, s2 = 0.f;
#pragma unroll
                    for (int i = 0; i < 8; ++i) { s1 += v1[i]; s2 += v2[i]; }
                    sm.agg.segs1[cl * 65 + ibase] = s1;
                    sm.agg.segs2[cl * 65 + ibase] = s2;
                }
                __syncthreads();

                {
                    float sv1 = sm.agg.segs1[wvw * 65 + lane];
                    float suf = sv1;
#pragma unroll
                    for (int off = 1; off < 64; off <<= 1) {
                        float u = __shfl_down(suf, off, 64);
                        if (lane + off < 64) suf += u;
                    }
                    sm.agg.segs1[wvw * 65 + lane] = suf - sv1;      // exclusive suffix
                    float sv2 = sm.agg.segs2[wvw * 65 + lane];
                    float pre = sv2;
#pragma unroll
                    for (int off = 1; off < 64; off <<= 1) {
                        float u = __shfl_up(pre, off, 64);
                        if (lane >= off) pre += u;
                    }
                    sm.agg.segs2[wvw * 65 + lane] = pre - sv2;      // exclusive prefix
                    if (lane == 63) sm.agg.tot[wvw] = pre;          // channel total
                }
                __syncthreads();

                {
                    float* b1 = sm.agg.A1 + cl * APW + ibase * 8;
                    float* b2 = sm.agg.A2 + cl * APW + ibase * 8;
                    float run = sm.agg.segs1[cl * 65 + ibase];
#pragma unroll
                    for (int i = 7; i >= 0; --i) { run += v1[i]; v1[i] = run; }      // incl suffix
                    float run2 = sm.agg.segs2[cl * 65 + ibase];
#pragma unroll
                    for (int i = 0; i < 8; ++i) { float tv = v2[i]; v2[i] = run2; run2 += tv; } // excl prefix
#pragma unroll
                    for (int q4 = 0; q4 < 2; ++q4) {
                        *(float4*)(b1 + q4 * 4) = make_float4(v1[q4 * 4], v1[q4 * 4 + 1],
                                                              v1[q4 * 4 + 2], v1[q4 * 4 + 3]);
                        *(float4*)(b2 + q4 * 4) = make_float4(v2[q4 * 4], v2[q4 * 4 + 1],
                                                              v2[q4 * 4 + 2], v2[q4 * 4 + 3]);
                    }
                }
                __syncthreads();

#pragma unroll
                for (int p = 0; p < 8; ++p) {
                    int i = p * 64 + ibase;
                    int k = sm.agg.kA[i];
                    float S1 = (k < 512) ? sm.agg.A1[cl * APW + k] : 0.f;
                    float P2 = (k < 512) ? sm.agg.A2[cl * APW + k] : sm.agg.tot[cl];
                    acc[p] += sm.agg.aZs[i] * S1 + sm.agg.bZs[i] * P2;
                }
            }

            const float bv = bias[c0 + cl];
#pragma unroll
            for (int p = 0; p < 8; ++p) {
                int i = p * 64 + ibase;
                xbuf[(size_t)(b * 512 + i) * 64 + c0 + cl] = fmaxf(0.25f * acc[p] + bv, 0.f);
            }
        }
        gridbar(bar + 3 * l + 2, G);
    }

    // ----------------------------------------------------------------------
    // Phase D: readout (64 virtual blocks)
    // ----------------------------------------------------------------------
    for (int vb = blockIdx.x; vb < 64; vb += G) {
        const int b = vb;
        __syncthreads();              // union safety
        int c = t & 63, q = t >> 6;
        float acc = 0.f;
        for (int n = q; n < 512; n += 4) acc += xbuf[((size_t)b * 512 + n) * 64 + c];
        sm.ro.red[q][c] = acc;
        __syncthreads();
        if (t < 64) sm.ro.pooled[t] = (sm.ro.red[0][t] + sm.ro.red[1][t] +
                                       sm.ro.red[2][t] + sm.ro.red[3][t]) * (1.0f / 512.0f);
        __syncthreads();
        if (t < 64) {
            float a = rbv[t];
            for (int cc = 0; cc < 64; ++cc) a += sm.ro.pooled[cc] * rw[t * 64 + cc];
            out[b * 64 + t] = a;
        }
    }
}

extern "C" void kernel_launch(void* const* d_in, const int* in_sizes, int n_in,
                              void* d_out, int out_size, void* d_ws, size_t ws_size,
                              hipStream_t stream) {
    const float* emb       = (const float*)d_in[0];
    const float* lin_w     = (const float*)d_in[1];
    const float* att_src   = (const float*)d_in[2];
    const float* att_dst   = (const float*)d_in[3];
    const float* conv_b    = (const float*)d_in[4];
    const float* readout_w = (const float*)d_in[5];
    const float* readout_b = (const float*)d_in[6];

    float* ws  = (float*)d_ws;
    int*   bar = (int*)(ws + 12000000);

    // Co-residency-safe grid size, computed ONCE from the compiled kernel's
    // actual resource usage (this is the R16 fix: never launch more blocks
    // than the occupancy API guarantees can be simultaneously resident).
    static int G = 0;
    if (G == 0) {
        int maxB = 0;
        if (hipOccupancyMaxActiveBlocksPerMultiprocessor(&maxB, mega_kernel, 256, 0) != hipSuccess || maxB < 1)
            maxB = 1;
        int dev = 0;
        hipGetDevice(&dev);
        int nCU = 0;
        if (hipDeviceGetAttribute(&nCU, hipDeviceAttributeMultiprocessorCount, dev) != hipSuccess || nCU < 1)
            nCU = 256;
        long cap = (long)maxB * (long)nCU;
        G = (int)(cap < 1024 ? cap : 1024);
        if (G < 1) G = 1;
    }

    // Zero the 9 one-shot barrier counters (ws is poisoned every iteration).
    hipMemsetAsync(bar, 0, 64, stream);
    mega_kernel<<<dim3(G), dim3(256), 0, stream>>>(emb, lin_w, att_src, att_dst,
                                                   conv_b, readout_w, readout_b,
                                                   (float*)d_out, ws);
}

// Round 2
// 615.333 us; speedup vs baseline: 1.2607x; 1.2607x over previous
//
#include <hip/hip_runtime.h>
#include <math.h>

// Problem constants (fixed by reference): B=64, N=512, D=64, H=4, C=64, L=3
// Workspace layout (floats), ws >= 256 MB:
//   xbuf [0 .. 2097152)         : layer activations x (8 MB)
//   hT   [2097152 .. 10485760)  : h TRANSPOSED [head][c][b*512+n] (32 MB)
//   meta [10485760 .. 11534336) : prep metadata + s/d dots (4 MB)
//   bar  [12000000 .. +1040 ints): release word + per-block arrive flags
// History: R15 multi-kernel = 266 us (known-good fallback).
// R17 mega-kernel: CORRECT but 776 us — post-mortem: 9 barriers x 1024
// serialized same-line far-atomic RMWs (~130 ns each) + 1024-wave spin storm
// = ~1200 us of pure barrier cost (VALUBusy 3.3% proved work unchanged).
// R18 (this): same proven phase bodies, contention-free barrier:
//   - arrival = one release-store per block to its OWN flag slot (no RMW)
//   - block 0 collects (256 threads poll 4KB in parallel), then one
//     release-store to a single release word (monotonic bno, no resets)
//   - spinners poll release with s_sleep(32) (~0.85us period)
//   - launch_bounds(256) uncapped; G from occupancy API (R16 trap fix kept)
// Fallback if >= 265 us: revert to R15 multi-kernel.

using short8  = __attribute__((ext_vector_type(8))) short;
using floatx4 = __attribute__((ext_vector_type(4))) float;

__device__ inline unsigned short f2bf(float f) {
    union { float f; unsigned u; } v; v.f = f;
    unsigned u = v.u + 0x7FFFu + ((v.u >> 16) & 1u);   // round-to-nearest-even
    return (unsigned short)(u >> 16);
}
__device__ inline float bf2f(unsigned short s) {
    union { float f; unsigned u; } v; v.u = ((unsigned)s) << 16;
    return v.f;
}

#define APW 516

// Per-phase shared memory, unioned (max ~24.8 KB -> 6 blocks/CU LDS-wise).
struct LinS {
    unsigned short WH[64 * 72], WL[64 * 72];
    unsigned short XH[16 * 72], XL[16 * 72];
    float sredS[4][16], sredD[4][16];
};
struct PrepS {
    float s_val[512];
    int   s_idxE[512];
    float z1suf[513], z2pre[513];
    float wred[8];
};
struct AggS {
    float A1[4 * APW], A2[4 * APW];
    float segs1[4 * 65], segs2[4 * 65];
    float tot[4];
    int   kA[512];
    float aZs[512], bZs[512];
};
struct RoS { float red[4][64]; float pooled[64]; };
union __align__(16) SMemU { LinS lin; PrepS prep; AggS agg; RoS ro; };

// Contention-free grid barrier, monotonic barrier number bno (1-based).
//   arrive[bid] = bno   (one release-store per block, own slot, no RMW)
//   block 0: poll all flags in parallel (256 threads), then release = bno
//   others : spin on release >= bno with long s_sleep
// Transitivity: writer --release-flag--> collector-acquire --release word-->
// spinner-acquire gives every block visibility of every other block's writes.
__device__ inline void gridbar(volatile int* release, int* arrive, int bno, int G) {
    __syncthreads();
    if (blockIdx.x == 0) {
        for (int i = threadIdx.x; i < G; i += 256) {
            if (i != 0) {
                while (__hip_atomic_load(&arrive[i], __ATOMIC_ACQUIRE,
                                         __HIP_MEMORY_SCOPE_AGENT) < bno)
                    __builtin_amdgcn_s_sleep(8);
            }
        }
        __syncthreads();                 // join all collector threads' acquires
        if (threadIdx.x == 0) {
            __threadfence();
            __hip_atomic_store((int*)release, bno, __ATOMIC_RELEASE,
                               __HIP_MEMORY_SCOPE_AGENT);
        }
    } else {
        if (threadIdx.x == 0) {
            __threadfence();
            __hip_atomic_store(&arrive[blockIdx.x], bno, __ATOMIC_RELEASE,
                               __HIP_MEMORY_SCOPE_AGENT);
            while (__hip_atomic_load((int*)release, __ATOMIC_ACQUIRE,
                                     __HIP_MEMORY_SCOPE_AGENT) < bno)
                __builtin_amdgcn_s_sleep(32);
        }
    }
    __syncthreads();
}

__global__ __launch_bounds__(256) void mega_kernel(
        const float* __restrict__ emb,
        const float* __restrict__ lin_w_all,
        const float* __restrict__ att_src_all,
        const float* __restrict__ att_dst_all,
        const float* __restrict__ conv_b_all,
        const float* __restrict__ rw,
        const float* __restrict__ rbv,
        float* __restrict__ out,
        float* __restrict__ ws) {
    __shared__ SMemU sm;

    float* xbuf = ws;                    // 8 MB
    float* hT   = ws + 2097152;          // 32 MB, [head][c][b*512+n]
    float* meta = ws + 10485760;         // 4 MB
    int*   g_sidx = (int*)meta;
    float* g_E1   = meta + 131072;
    float* g_E2   = meta + 262144;
    float* g_aZ   = meta + 393216;
    float* g_bZ   = meta + 524288;
    int*   g_k    = (int*)(meta + 655360);
    float* g_s    = meta + 786432;
    float* g_d    = meta + 917504;
    volatile int* release = (volatile int*)(ws + 12000000);
    int*          arrive  = (int*)(ws + 12000000) + 16;   // [1024]

    const int t = threadIdx.x;
    const int G = gridDim.x;
    int bno = 0;

    for (int l = 0; l < 3; ++l) {
        const float* xin     = (l == 0) ? emb : xbuf;
        const float* W       = lin_w_all + (size_t)l * 16384;
        const float* att_src = att_src_all + l * 256;
        const float* att_dst = att_dst_all + l * 256;
        const float* bias    = conv_b_all + l * 64;

        // ------------------------------------------------------------------
        // Phase A: lin (2048 virtual blocks) — MFMA split-bf16
        // ------------------------------------------------------------------
        for (int vb = blockIdx.x; vb < 2048; vb += G) {
            const int ct = vb >> 9;       // head 0..3
            const int rb = vb & 511;      // row-block (4 rt tiles)
            const int c0 = ct * 64;
            __syncthreads();              // union safety across vb iterations

#pragma unroll
            for (int q = 0; q < 4; ++q) {
                int f = q * 256 + t;
                int wrow = f >> 4, d4 = f & 15;
                float4 v = *(const float4*)(W + (size_t)(c0 + wrow) * 64 + d4 * 4);
                unsigned short h0 = f2bf(v.x), h1 = f2bf(v.y), h2 = f2bf(v.z), h3 = f2bf(v.w);
                ushort4 hi = make_ushort4(h0, h1, h2, h3);
                ushort4 lo = make_ushort4(f2bf(v.x - bf2f(h0)), f2bf(v.y - bf2f(h1)),
                                          f2bf(v.z - bf2f(h2)), f2bf(v.w - bf2f(h3)));
                *(ushort4*)&sm.lin.WH[wrow * 72 + d4 * 4] = hi;
                *(ushort4*)&sm.lin.WL[wrow * 72 + d4 * 4] = lo;
            }
            __syncthreads();

            const int lane = t & 63, wv = t >> 6;
            const int mrow = lane & 15, quad = lane >> 4;
            const int c = wv * 16 + mrow;

            short8 bh[2], bl[2];
#pragma unroll
            for (int kk = 0; kk < 2; ++kk) {
                int ko = kk * 32 + quad * 8;
                bh[kk] = *(const short8*)&sm.lin.WH[(wv * 16 + mrow) * 72 + ko];
                bl[kk] = *(const short8*)&sm.lin.WL[(wv * 16 + mrow) * 72 + ko];
            }
            const float as_c = att_src[c0 + c];
            const float ad_c = att_dst[c0 + c];

#pragma unroll 1
            for (int tt = 0; tt < 4; ++tt) {
                const int rt = rb * 4 + tt;
                const int r0 = rt * 16;
                __syncthreads();

                {
                    int row = t >> 4, d4 = t & 15;
                    float4 v = *(const float4*)(xin + (size_t)(r0 + row) * 64 + d4 * 4);
                    unsigned short h0 = f2bf(v.x), h1 = f2bf(v.y), h2 = f2bf(v.z), h3 = f2bf(v.w);
                    ushort4 hi = make_ushort4(h0, h1, h2, h3);
                    ushort4 lo = make_ushort4(f2bf(v.x - bf2f(h0)), f2bf(v.y - bf2f(h1)),
                                              f2bf(v.z - bf2f(h2)), f2bf(v.w - bf2f(h3)));
                    *(ushort4*)&sm.lin.XH[row * 72 + d4 * 4] = hi;
                    *(ushort4*)&sm.lin.XL[row * 72 + d4 * 4] = lo;
                }
                __syncthreads();

                short8 ah[2], al[2];
#pragma unroll
                for (int kk = 0; kk < 2; ++kk) {
                    int ko = kk * 32 + quad * 8;
                    ah[kk] = *(const short8*)&sm.lin.XH[mrow * 72 + ko];
                    al[kk] = *(const short8*)&sm.lin.XL[mrow * 72 + ko];
                }

                floatx4 acc = {0.f, 0.f, 0.f, 0.f};
                acc = __builtin_amdgcn_mfma_f32_16x16x32_bf16(ah[0], bh[0], acc, 0, 0, 0);
                acc = __builtin_amdgcn_mfma_f32_16x16x32_bf16(ah[1], bh[1], acc, 0, 0, 0);
                acc = __builtin_amdgcn_mfma_f32_16x16x32_bf16(ah[0], bl[0], acc, 0, 0, 0);
                acc = __builtin_amdgcn_mfma_f32_16x16x32_bf16(ah[1], bl[1], acc, 0, 0, 0);
                acc = __builtin_amdgcn_mfma_f32_16x16x32_bf16(al[0], bh[0], acc, 0, 0, 0);
                acc = __builtin_amdgcn_mfma_f32_16x16x32_bf16(al[1], bh[1], acc, 0, 0, 0);

                *(float4*)&hT[(size_t)(ct * 64 + c) * 32768 + r0 + quad * 4] =
                    make_float4(acc[0], acc[1], acc[2], acc[3]);

                float ps[4], pd[4];
#pragma unroll
                for (int reg = 0; reg < 4; ++reg) { ps[reg] = acc[reg] * as_c; pd[reg] = acc[reg] * ad_c; }
#pragma unroll
                for (int m = 1; m <= 8; m <<= 1) {
#pragma unroll
                    for (int reg = 0; reg < 4; ++reg) {
                        ps[reg] += __shfl_xor(ps[reg], m, 64);
                        pd[reg] += __shfl_xor(pd[reg], m, 64);
                    }
                }
                if (mrow < 4) {
                    sm.lin.sredS[wv][quad * 4 + mrow] = ps[mrow];
                    sm.lin.sredD[wv][quad * 4 + mrow] = pd[mrow];
                }
                __syncthreads();
                if (t < 16) {
                    float sS = sm.lin.sredS[0][t] + sm.lin.sredS[1][t] + sm.lin.sredS[2][t] + sm.lin.sredS[3][t];
                    float sD = sm.lin.sredD[0][t] + sm.lin.sredD[1][t] + sm.lin.sredD[2][t] + sm.lin.sredD[3][t];
                    int gn = r0 + t;
                    int bh2 = (gn >> 9) * 4 + ct;
                    int n  = gn & 511;
                    g_s[bh2 * 512 + n] = sS;
                    g_d[bh2 * 512 + n] = sD;
                }
            }
        }
        gridbar(release, arrive, ++bno, G);

        // ------------------------------------------------------------------
        // Phase B: attn_prep (256 virtual blocks) — bitonic sort + wave scans
        // ------------------------------------------------------------------
        for (int vb = blockIdx.x; vb < 256; vb += G) {
            const int bh = vb;
            const int lane = t & 63;
            const int wid = t >> 6;
            __syncthreads();              // union safety

            float dreg[2];
            for (int rr = 0; rr < 2; ++rr) {
                int j = t + rr * 256;
                sm.prep.s_val[j] = g_s[bh * 512 + j];
                dreg[rr] = g_d[bh * 512 + j];
            }
            __syncthreads();

            float v0 = sm.prep.s_val[2 * t], v1 = sm.prep.s_val[2 * t + 1];
            int id0 = 2 * t, id1 = 2 * t + 1;
            for (int k = 2; k <= 512; k <<= 1) {
                for (int j = k >> 1; j >= 1; j >>= 1) {
                    bool asc = ((t & (k >> 1)) == 0);
                    if (j == 1) {
                        bool sw = asc ? (v0 > v1) : (v0 < v1);
                        if (sw) { float tv = v0; v0 = v1; v1 = tv; int ti = id0; id0 = id1; id1 = ti; }
                    } else if (j <= 64) {
                        int m = j >> 1;
                        float w0 = __shfl_xor(v0, m, 64);
                        int  wi0 = __shfl_xor(id0, m, 64);
                        float w1 = __shfl_xor(v1, m, 64);
                        int  wi1 = __shfl_xor(id1, m, 64);
                        bool low = ((t & m) == 0);
                        bool wantmin = (low == asc);
                        if (wantmin ? (w0 < v0) : (w0 > v0)) { v0 = w0; id0 = wi0; }
                        if (wantmin ? (w1 < v1) : (w1 > v1)) { v1 = w1; id1 = wi1; }
                    } else {
                        int m = j >> 1;
                        sm.prep.s_val[2 * t] = v0; sm.prep.s_val[2 * t + 1] = v1;
                        sm.prep.s_idxE[2 * t] = id0; sm.prep.s_idxE[2 * t + 1] = id1;
                        __syncthreads();
                        int tp = t ^ m;
                        float w0 = sm.prep.s_val[2 * tp], w1 = sm.prep.s_val[2 * tp + 1];
                        int wi0 = sm.prep.s_idxE[2 * tp], wi1 = sm.prep.s_idxE[2 * tp + 1];
                        bool low = ((t & m) == 0);
                        bool wantmin = (low == asc);
                        if (wantmin ? (w0 < v0) : (w0 > v0)) { v0 = w0; id0 = wi0; }
                        if (wantmin ? (w1 < v1) : (w1 > v1)) { v1 = w1; id1 = wi1; }
                        __syncthreads();
                    }
                }
            }

            sm.prep.s_val[2 * t] = v0; sm.prep.s_val[2 * t + 1] = v1;
            __syncthreads();
            const float M = sm.prep.s_val[511];
            float e1_0 = __expf(v0 - M), e1_1 = __expf(v1 - M);
            float e2_0 = __expf(0.2f * (v0 - M)), e2_1 = __expf(0.2f * (v1 - M));
            *(float2*)(g_E1 + bh * 512 + 2 * t) = make_float2(e1_0, e1_1);
            *(float2*)(g_E2 + bh * 512 + 2 * t) = make_float2(e2_0, e2_1);
            *(int2*)(g_sidx + bh * 512 + 2 * t) = make_int2(id0, id1);

            float S1 = e1_0 + e1_1, S2 = e2_0 + e2_1;
            float i1 = S1, i2 = S2;
            for (int off = 1; off < 64; off <<= 1) {
                float u1 = __shfl_up(i1, off, 64);
                float u2 = __shfl_up(i2, off, 64);
                if (lane >= off) { i1 += u1; i2 += u2; }
            }
            if (lane == 63) { sm.prep.wred[wid] = i1; sm.prep.wred[4 + wid] = i2; }
            __syncthreads();
            float off1 = 0.f, off2 = 0.f;
            for (int w = 0; w < wid; ++w) { off1 += sm.prep.wred[w]; off2 += sm.prep.wred[4 + w]; }
            const float T1 = sm.prep.wred[0] + sm.prep.wred[1] + sm.prep.wred[2] + sm.prep.wred[3];
            const float T2 = sm.prep.wred[4] + sm.prep.wred[5] + sm.prep.wred[6] + sm.prep.wred[7];
            float pre1 = off1 + i1 - S1;
            float pre2 = off2 + i2 - S2;
            sm.prep.z1suf[2 * t] = T1 - pre1;
            sm.prep.z1suf[2 * t + 1] = T1 - pre1 - e1_0;
            sm.prep.z2pre[2 * t] = pre2;
            sm.prep.z2pre[2 * t + 1] = pre2 + e2_0;
            if (t == 0) { sm.prep.z1suf[512] = 0.f; sm.prep.z2pre[512] = T2; }
            __syncthreads();

            for (int rr = 0; rr < 2; ++rr) {
                int i = t + rr * 256;
                float d = dreg[rr];
                int lo = 0, hi = 512;
                while (lo < hi) {
                    int mid = (lo + hi) >> 1;
                    if (d + sm.prep.s_val[mid] >= 0.f) hi = mid; else lo = mid + 1;
                }
                int k = lo;
                float g = d + M;
                float Gv = (g >= 0.f) ? g : 0.2f * g;
                float al = __expf(g - Gv);
                float be = __expf(0.2f * g - Gv);
                float Z = al * sm.prep.z1suf[k] + be * sm.prep.z2pre[k];
                float inv = 1.0f / Z;
                g_aZ[bh * 512 + i] = al * inv;
                g_bZ[bh * 512 + i] = be * inv;
                g_k[bh * 512 + i]  = k;
            }
        }
        gridbar(release, arrive, ++bno, G);

        // ------------------------------------------------------------------
        // Phase C: attn_agg_fin (1024 virtual blocks)
        // ------------------------------------------------------------------
        for (int vb = blockIdx.x; vb < 1024; vb += G) {
            const int b  = vb & 63;
            const int cg = vb >> 6;        // 0..15
            const int c0 = cg * 4;
            const int lane = t & 63, wvw = t >> 6;
            const int cl = t & 3, ibase = t >> 2;  // cl: channel, ibase: seg 0..63

            float acc[8];
#pragma unroll
            for (int p = 0; p < 8; ++p) acc[p] = 0.f;

#pragma unroll 1
            for (int head = 0; head < 4; ++head) {
                const int bh = b * 4 + head;
                const float* hTb = hT + (size_t)(head * 64 + c0) * 32768 + b * 512;
                __syncthreads();   // prev head's (or prev phase's) reads done

                for (int rr = 0; rr < 2; ++rr) {
                    int r = t + rr * 256;
                    int j = g_sidx[bh * 512 + r];
                    float e1 = g_E1[bh * 512 + r];
                    float e2 = g_E2[bh * 512 + r];
                    sm.agg.kA[r]  = g_k[bh * 512 + r];
                    sm.agg.aZs[r] = g_aZ[bh * 512 + r];
                    sm.agg.bZs[r] = g_bZ[bh * 512 + r];
#pragma unroll
                    for (int c = 0; c < 4; ++c) {
                        float hvv = hTb[c * 32768 + j];
                        sm.agg.A1[c * APW + r] = e1 * hvv;
                        sm.agg.A2[c * APW + r] = e2 * hvv;
                    }
                }
                __syncthreads();

                float v1[8], v2[8];
                {
                    float* b1 = sm.agg.A1 + cl * APW + ibase * 8;
                    float* b2 = sm.agg.A2 + cl * APW + ibase * 8;
#pragma unroll
                    for (int q4 = 0; q4 < 2; ++q4) {
                        float4 a = *(const float4*)(b1 + q4 * 4);
                        v1[q4 * 4] = a.x; v1[q4 * 4 + 1] = a.y; v1[q4 * 4 + 2] = a.z; v1[q4 * 4 + 3] = a.w;
                        float4 c2 = *(const float4*)(b2 + q4 * 4);
                        v2[q4 * 4] = c2.x; v2[q4 * 4 + 1] = c2.y; v2[q4 * 4 + 2] = c2.z; v2[q4 * 4 + 3] = c2.w;
                    }
                    float s1 = 0.f, s2 = 0.f;
#pragma unroll
                    for (int i = 0; i < 8; ++i) { s1 += v1[i]; s2 += v2[i]; }
                    sm.agg.segs1[cl * 65 + ibase] = s1;
                    sm.agg.segs2[cl * 65 + ibase] = s2;
                }
                __syncthreads();

                {
                    float sv1 = sm.agg.segs1[wvw * 65 + lane];
                    float suf = sv1;
#pragma unroll
                    for (int off = 1; off < 64; off <<= 1) {
                        float u = __shfl_down(suf, off, 64);
                        if (lane + off < 64) suf += u;
                    }
                    sm.agg.segs1[wvw * 65 + lane] = suf - sv1;      // exclusive suffix
                    float sv2 = sm.agg.segs2[wvw * 65 + lane];
                    float pre = sv2;
#pragma unroll
                    for (int off = 1; off < 64; off <<= 1) {
                        float u = __shfl_up(pre, off, 64);
                        if (lane >= off) pre += u;
                    }
                    sm.agg.segs2[wvw * 65 + lane] = pre - sv2;      // exclusive prefix
                    if (lane == 63) sm.agg.tot[wvw] = pre;          // channel total
                }
                __syncthreads();

                {
                    float* b1 = sm.agg.A1 + cl * APW + ibase * 8;
                    float* b2 = sm.agg.A2 + cl * APW + ibase * 8;
                    float run = sm.agg.segs1[cl * 65 + ibase];
#pragma unroll
                    for (int i = 7; i >= 0; --i) { run += v1[i]; v1[i] = run; }      // incl suffix
                    float run2 = sm.agg.segs2[cl * 65 + ibase];
#pragma unroll
                    for (int i = 0; i < 8; ++i) { float tv = v2[i]; v2[i] = run2; run2 += tv; } // excl prefix
#pragma unroll
                    for (int q4 = 0; q4 < 2; ++q4) {
                        *(float4*)(b1 + q4 * 4) = make_float4(v1[q4 * 4], v1[q4 * 4 + 1],
                                                              v1[q4 * 4 + 2], v1[q4 * 4 + 3]);
                        *(float4*)(b2 + q4 * 4) = make_float4(v2[q4 * 4], v2[q4 * 4 + 1],
                                                              v2[q4 * 4 + 2], v2[q4 * 4 + 3]);
                    }
                }
                __syncthreads();

#pragma unroll
                for (int p = 0; p < 8; ++p) {
                    int i = p * 64 + ibase;
                    int k = sm.agg.kA[i];
                    float S1 = (k < 512) ? sm.agg.A1[cl * APW + k] : 0.f;
                    float P2 = (k < 512) ? sm.agg.A2[cl * APW + k] : sm.agg.tot[cl];
                    acc[p] += sm.agg.aZs[i] * S1 + sm.agg.bZs[i] * P2;
                }
            }

            const float bv = bias[c0 + cl];
#pragma unroll
            for (int p = 0; p < 8; ++p) {
                int i = p * 64 + ibase;
                xbuf[(size_t)(b * 512 + i) * 64 + c0 + cl] = fmaxf(0.25f * acc[p] + bv, 0.f);
            }
        }
        gridbar(release, arrive, ++bno, G);
    }

    // ----------------------------------------------------------------------
    // Phase D: readout (64 virtual blocks)
    // ----------------------------------------------------------------------
    for (int vb = blockIdx.x; vb < 64; vb += G) {
        const int b = vb;
        __syncthreads();              // union safety
        int c = t & 63, q = t >> 6;
        float acc = 0.f;
        for (int n = q; n < 512; n += 4) acc += xbuf[((size_t)b * 512 + n) * 64 + c];
        sm.ro.red[q][c] = acc;
        __syncthreads();
        if (t < 64) sm.ro.pooled[t] = (sm.ro.red[0][t] + sm.ro.red[1][t] +
                                       sm.ro.red[2][t] + sm.ro.red[3][t]) * (1.0f / 512.0f);
        __syncthreads();
        if (t < 64) {
            float a = rbv[t];
            for (int cc = 0; cc < 64; ++cc) a += sm.ro.pooled[cc] * rw[t * 64 + cc];
            out[b * 64 + t] = a;
        }
    }
}

extern "C" void kernel_launch(void* const* d_in, const int* in_sizes, int n_in,
                              void* d_out, int out_size, void* d_ws, size_t ws_size,
                              hipStream_t stream) {
    const float* emb       = (const float*)d_in[0];
    const float* lin_w     = (const float*)d_in[1];
    const float* att_src   = (const float*)d_in[2];
    const float* att_dst   = (const float*)d_in[3];
    const float* conv_b    = (const float*)d_in[4];
    const float* readout_w = (const float*)d_in[5];
    const float* readout_b = (const float*)d_in[6];

    float* ws  = (float*)d_ws;
    int*   bar = (int*)(ws + 12000000);    // release[16] + arrive[1024]

    // Co-residency-safe grid size from the compiled kernel's actual resource
    // usage (R16 trap fix: never launch more than guaranteed-resident).
    static int G = 0;
    if (G == 0) {
        int maxB = 0;
        if (hipOccupancyMaxActiveBlocksPerMultiprocessor(&maxB, mega_kernel, 256, 0) != hipSuccess || maxB < 1)
            maxB = 1;
        int dev = 0;
        hipGetDevice(&dev);
        int nCU = 0;
        if (hipDeviceGetAttribute(&nCU, hipDeviceAttributeMultiprocessorCount, dev) != hipSuccess || nCU < 1)
            nCU = 256;
        long cap = (long)maxB * (long)nCU;
        G = (int)(cap < 1024 ? cap : 1024);
        if (G < 1) G = 1;
    }

    // Zero release word(s) + per-block arrival flags (ws poisoned every iter).
    hipMemsetAsync(bar, 0, (16 + 1024) * sizeof(int), stream);
    mega_kernel<<<dim3(G), dim3(256), 0, stream>>>(emb, lin_w, att_src, att_dst,
                                                   conv_b, readout_w, readout_b,
                                                   (float*)d_out, ws);
}

// Round 3
// 460.623 us; speedup vs baseline: 1.6842x; 1.3359x over previous
//
#include <hip/hip_runtime.h>
#include <math.h>

// Problem constants (fixed by reference): B=64, N=512, D=64, H=4, C=64, L=3
// Workspace layout (floats), ws >= 256 MB:
//   xbuf [0 .. 2097152)         : layer activations x (8 MB)
//   hT   [2097152 .. 10485760)  : h TRANSPOSED [head][c][b*512+n] (32 MB)
//   meta [10485760 .. 11534336) : prep metadata + s/d dots (4 MB)
//   bar  [12000000 .. +1040 ints): release word + per-block arrive flags
// History: R15 multi-kernel = 266 us (known-good fallback).
// R17 mega: 776 us — 1024 serialized same-line RMWs + acquire-poll storm.
// R18 mega: 615 us — RMW gone, but ~45 us/barrier REMAINS. Post-mortem:
//   per-poll ACQUIRE loads emit buffer_inv (full XCD-L2 invalidate) on
//   gfx940+ agent scope -> ~768 spinners invalidate every XCD's L2 every
//   ~9 ns while working blocks run -> phases run cache-less.
// R19 (this): cache-neutral spin. Poll with RELAXED agent loads (plain sc1
//   load, NO buffer_inv), then ONE acquire fence per block per barrier after
//   the spin exits. Release-store arrival (one wbl2) kept for cross-XCD
//   visibility. Shorter sleeps (8/16) now that polls are cache-neutral.
// DECISION RULE: if >= 265 us, revert to R15 multi-kernel next round.

using short8  = __attribute__((ext_vector_type(8))) short;
using floatx4 = __attribute__((ext_vector_type(4))) float;

__device__ inline unsigned short f2bf(float f) {
    union { float f; unsigned u; } v; v.f = f;
    unsigned u = v.u + 0x7FFFu + ((v.u >> 16) & 1u);   // round-to-nearest-even
    return (unsigned short)(u >> 16);
}
__device__ inline float bf2f(unsigned short s) {
    union { float f; unsigned u; } v; v.u = ((unsigned)s) << 16;
    return v.f;
}

#define APW 516

// Per-phase shared memory, unioned (max ~24.8 KB).
struct LinS {
    unsigned short WH[64 * 72], WL[64 * 72];
    unsigned short XH[16 * 72], XL[16 * 72];
    float sredS[4][16], sredD[4][16];
};
struct PrepS {
    float s_val[512];
    int   s_idxE[512];
    float z1suf[513], z2pre[513];
    float wred[8];
};
struct AggS {
    float A1[4 * APW], A2[4 * APW];
    float segs1[4 * 65], segs2[4 * 65];
    float tot[4];
    int   kA[512];
    float aZs[512], bZs[512];
};
struct RoS { float red[4][64]; float pooled[64]; };
union __align__(16) SMemU { LinS lin; PrepS prep; AggS agg; RoS ro; };

// Contention-free, CACHE-NEUTRAL grid barrier (monotonic bno, 1-based).
//   arrival : one release-store per block to its own slot (wbl2 publishes
//             the block's phase writes to the agent coherence point)
//   collect : block 0's 256 threads poll flags with RELAXED loads (no inv)
//   release : one release-store to a single word; spinners poll RELAXED,
//             then issue ONE acquire fence (one buffer_inv) before exiting.
__device__ inline void gridbar(int* release, int* arrive, int bno, int G) {
    __syncthreads();
    if (blockIdx.x == 0) {
        for (int i = threadIdx.x; i < G; i += 256) {
            if (i != 0) {
                while (__hip_atomic_load(&arrive[i], __ATOMIC_RELAXED,
                                         __HIP_MEMORY_SCOPE_AGENT) < bno)
                    __builtin_amdgcn_s_sleep(8);
            }
        }
        __syncthreads();                 // all collector threads done polling
        if (threadIdx.x == 0) {
            __atomic_thread_fence(__ATOMIC_ACQUIRE);   // one inv: pull in all
            __hip_atomic_store(release, bno, __ATOMIC_RELEASE,
                               __HIP_MEMORY_SCOPE_AGENT);
        }
    } else {
        if (threadIdx.x == 0) {
            __hip_atomic_store(&arrive[blockIdx.x], bno, __ATOMIC_RELEASE,
                               __HIP_MEMORY_SCOPE_AGENT);
            while (__hip_atomic_load(release, __ATOMIC_RELAXED,
                                     __HIP_MEMORY_SCOPE_AGENT) < bno)
                __builtin_amdgcn_s_sleep(16);
            __atomic_thread_fence(__ATOMIC_ACQUIRE);   // one inv per barrier
        }
    }
    __syncthreads();
}

__global__ __launch_bounds__(256) void mega_kernel(
        const float* __restrict__ emb,
        const float* __restrict__ lin_w_all,
        const float* __restrict__ att_src_all,
        const float* __restrict__ att_dst_all,
        const float* __restrict__ conv_b_all,
        const float* __restrict__ rw,
        const float* __restrict__ rbv,
        float* __restrict__ out,
        float* __restrict__ ws) {
    __shared__ SMemU sm;

    float* xbuf = ws;                    // 8 MB
    float* hT   = ws + 2097152;          // 32 MB, [head][c][b*512+n]
    float* meta = ws + 10485760;         // 4 MB
    int*   g_sidx = (int*)meta;
    float* g_E1   = meta + 131072;
    float* g_E2   = meta + 262144;
    float* g_aZ   = meta + 393216;
    float* g_bZ   = meta + 524288;
    int*   g_k    = (int*)(meta + 655360);
    float* g_s    = meta + 786432;
    float* g_d    = meta + 917504;
    int*   release = (int*)(ws + 12000000);
    int*   arrive  = (int*)(ws + 12000000) + 16;   // [1024]

    const int t = threadIdx.x;
    const int G = gridDim.x;
    int bno = 0;

    for (int l = 0; l < 3; ++l) {
        const float* xin     = (l == 0) ? emb : xbuf;
        const float* W       = lin_w_all + (size_t)l * 16384;
        const float* att_src = att_src_all + l * 256;
        const float* att_dst = att_dst_all + l * 256;
        const float* bias    = conv_b_all + l * 64;

        // ------------------------------------------------------------------
        // Phase A: lin (2048 virtual blocks) — MFMA split-bf16
        // ------------------------------------------------------------------
        for (int vb = blockIdx.x; vb < 2048; vb += G) {
            const int ct = vb >> 9;       // head 0..3
            const int rb = vb & 511;      // row-block (4 rt tiles)
            const int c0 = ct * 64;
            __syncthreads();              // union safety across vb iterations

#pragma unroll
            for (int q = 0; q < 4; ++q) {
                int f = q * 256 + t;
                int wrow = f >> 4, d4 = f & 15;
                float4 v = *(const float4*)(W + (size_t)(c0 + wrow) * 64 + d4 * 4);
                unsigned short h0 = f2bf(v.x), h1 = f2bf(v.y), h2 = f2bf(v.z), h3 = f2bf(v.w);
                ushort4 hi = make_ushort4(h0, h1, h2, h3);
                ushort4 lo = make_ushort4(f2bf(v.x - bf2f(h0)), f2bf(v.y - bf2f(h1)),
                                          f2bf(v.z - bf2f(h2)), f2bf(v.w - bf2f(h3)));
                *(ushort4*)&sm.lin.WH[wrow * 72 + d4 * 4] = hi;
                *(ushort4*)&sm.lin.WL[wrow * 72 + d4 * 4] = lo;
            }
            __syncthreads();

            const int lane = t & 63, wv = t >> 6;
            const int mrow = lane & 15, quad = lane >> 4;
            const int c = wv * 16 + mrow;

            short8 bh[2], bl[2];
#pragma unroll
            for (int kk = 0; kk < 2; ++kk) {
                int ko = kk * 32 + quad * 8;
                bh[kk] = *(const short8*)&sm.lin.WH[(wv * 16 + mrow) * 72 + ko];
                bl[kk] = *(const short8*)&sm.lin.WL[(wv * 16 + mrow) * 72 + ko];
            }
            const float as_c = att_src[c0 + c];
            const float ad_c = att_dst[c0 + c];

#pragma unroll 1
            for (int tt = 0; tt < 4; ++tt) {
                const int rt = rb * 4 + tt;
                const int r0 = rt * 16;
                __syncthreads();

                {
                    int row = t >> 4, d4 = t & 15;
                    float4 v = *(const float4*)(xin + (size_t)(r0 + row) * 64 + d4 * 4);
                    unsigned short h0 = f2bf(v.x), h1 = f2bf(v.y), h2 = f2bf(v.z), h3 = f2bf(v.w);
                    ushort4 hi = make_ushort4(h0, h1, h2, h3);
                    ushort4 lo = make_ushort4(f2bf(v.x - bf2f(h0)), f2bf(v.y - bf2f(h1)),
                                              f2bf(v.z - bf2f(h2)), f2bf(v.w - bf2f(h3)));
                    *(ushort4*)&sm.lin.XH[row * 72 + d4 * 4] = hi;
                    *(ushort4*)&sm.lin.XL[row * 72 + d4 * 4] = lo;
                }
                __syncthreads();

                short8 ah[2], al[2];
#pragma unroll
                for (int kk = 0; kk < 2; ++kk) {
                    int ko = kk * 32 + quad * 8;
                    ah[kk] = *(const short8*)&sm.lin.XH[mrow * 72 + ko];
                    al[kk] = *(const short8*)&sm.lin.XL[mrow * 72 + ko];
                }

                floatx4 acc = {0.f, 0.f, 0.f, 0.f};
                acc = __builtin_amdgcn_mfma_f32_16x16x32_bf16(ah[0], bh[0], acc, 0, 0, 0);
                acc = __builtin_amdgcn_mfma_f32_16x16x32_bf16(ah[1], bh[1], acc, 0, 0, 0);
                acc = __builtin_amdgcn_mfma_f32_16x16x32_bf16(ah[0], bl[0], acc, 0, 0, 0);
                acc = __builtin_amdgcn_mfma_f32_16x16x32_bf16(ah[1], bl[1], acc, 0, 0, 0);
                acc = __builtin_amdgcn_mfma_f32_16x16x32_bf16(al[0], bh[0], acc, 0, 0, 0);
                acc = __builtin_amdgcn_mfma_f32_16x16x32_bf16(al[1], bh[1], acc, 0, 0, 0);

                *(float4*)&hT[(size_t)(ct * 64 + c) * 32768 + r0 + quad * 4] =
                    make_float4(acc[0], acc[1], acc[2], acc[3]);

                float ps[4], pd[4];
#pragma unroll
                for (int reg = 0; reg < 4; ++reg) { ps[reg] = acc[reg] * as_c; pd[reg] = acc[reg] * ad_c; }
#pragma unroll
                for (int m = 1; m <= 8; m <<= 1) {
#pragma unroll
                    for (int reg = 0; reg < 4; ++reg) {
                        ps[reg] += __shfl_xor(ps[reg], m, 64);
                        pd[reg] += __shfl_xor(pd[reg], m, 64);
                    }
                }
                if (mrow < 4) {
                    sm.lin.sredS[wv][quad * 4 + mrow] = ps[mrow];
                    sm.lin.sredD[wv][quad * 4 + mrow] = pd[mrow];
                }
                __syncthreads();
                if (t < 16) {
                    float sS = sm.lin.sredS[0][t] + sm.lin.sredS[1][t] + sm.lin.sredS[2][t] + sm.lin.sredS[3][t];
                    float sD = sm.lin.sredD[0][t] + sm.lin.sredD[1][t] + sm.lin.sredD[2][t] + sm.lin.sredD[3][t];
                    int gn = r0 + t;
                    int bh2 = (gn >> 9) * 4 + ct;
                    int n  = gn & 511;
                    g_s[bh2 * 512 + n] = sS;
                    g_d[bh2 * 512 + n] = sD;
                }
            }
        }
        gridbar(release, arrive, ++bno, G);

        // ------------------------------------------------------------------
        // Phase B: attn_prep (256 virtual blocks) — bitonic sort + wave scans
        // ------------------------------------------------------------------
        for (int vb = blockIdx.x; vb < 256; vb += G) {
            const int bh = vb;
            const int lane = t & 63;
            const int wid = t >> 6;
            __syncthreads();              // union safety

            float dreg[2];
            for (int rr = 0; rr < 2; ++rr) {
                int j = t + rr * 256;
                sm.prep.s_val[j] = g_s[bh * 512 + j];
                dreg[rr] = g_d[bh * 512 + j];
            }
            __syncthreads();

            float v0 = sm.prep.s_val[2 * t], v1 = sm.prep.s_val[2 * t + 1];
            int id0 = 2 * t, id1 = 2 * t + 1;
            for (int k = 2; k <= 512; k <<= 1) {
                for (int j = k >> 1; j >= 1; j >>= 1) {
                    bool asc = ((t & (k >> 1)) == 0);
                    if (j == 1) {
                        bool sw = asc ? (v0 > v1) : (v0 < v1);
                        if (sw) { float tv = v0; v0 = v1; v1 = tv; int ti = id0; id0 = id1; id1 = ti; }
                    } else if (j <= 64) {
                        int m = j >> 1;
                        float w0 = __shfl_xor(v0, m, 64);
                        int  wi0 = __shfl_xor(id0, m, 64);
                        float w1 = __shfl_xor(v1, m, 64);
                        int  wi1 = __shfl_xor(id1, m, 64);
                        bool low = ((t & m) == 0);
                        bool wantmin = (low == asc);
                        if (wantmin ? (w0 < v0) : (w0 > v0)) { v0 = w0; id0 = wi0; }
                        if (wantmin ? (w1 < v1) : (w1 > v1)) { v1 = w1; id1 = wi1; }
                    } else {
                        int m = j >> 1;
                        sm.prep.s_val[2 * t] = v0; sm.prep.s_val[2 * t + 1] = v1;
                        sm.prep.s_idxE[2 * t] = id0; sm.prep.s_idxE[2 * t + 1] = id1;
                        __syncthreads();
                        int tp = t ^ m;
                        float w0 = sm.prep.s_val[2 * tp], w1 = sm.prep.s_val[2 * tp + 1];
                        int wi0 = sm.prep.s_idxE[2 * tp], wi1 = sm.prep.s_idxE[2 * tp + 1];
                        bool low = ((t & m) == 0);
                        bool wantmin = (low == asc);
                        if (wantmin ? (w0 < v0) : (w0 > v0)) { v0 = w0; id0 = wi0; }
                        if (wantmin ? (w1 < v1) : (w1 > v1)) { v1 = w1; id1 = wi1; }
                        __syncthreads();
                    }
                }
            }

            sm.prep.s_val[2 * t] = v0; sm.prep.s_val[2 * t + 1] = v1;
            __syncthreads();
            const float M = sm.prep.s_val[511];
            float e1_0 = __expf(v0 - M), e1_1 = __expf(v1 - M);
            float e2_0 = __expf(0.2f * (v0 - M)), e2_1 = __expf(0.2f * (v1 - M));
            *(float2*)(g_E1 + bh * 512 + 2 * t) = make_float2(e1_0, e1_1);
            *(float2*)(g_E2 + bh * 512 + 2 * t) = make_float2(e2_0, e2_1);
            *(int2*)(g_sidx + bh * 512 + 2 * t) = make_int2(id0, id1);

            float S1 = e1_0 + e1_1, S2 = e2_0 + e2_1;
            float i1 = S1, i2 = S2;
            for (int off = 1; off < 64; off <<= 1) {
                float u1 = __shfl_up(i1, off, 64);
                float u2 = __shfl_up(i2, off, 64);
                if (lane >= off) { i1 += u1; i2 += u2; }
            }
            if (lane == 63) { sm.prep.wred[wid] = i1; sm.prep.wred[4 + wid] = i2; }
            __syncthreads();
            float off1 = 0.f, off2 = 0.f;
            for (int w = 0; w < wid; ++w) { off1 += sm.prep.wred[w]; off2 += sm.prep.wred[4 + w]; }
            const float T1 = sm.prep.wred[0] + sm.prep.wred[1] + sm.prep.wred[2] + sm.prep.wred[3];
            const float T2 = sm.prep.wred[4] + sm.prep.wred[5] + sm.prep.wred[6] + sm.prep.wred[7];
            float pre1 = off1 + i1 - S1;
            float pre2 = off2 + i2 - S2;
            sm.prep.z1suf[2 * t] = T1 - pre1;
            sm.prep.z1suf[2 * t + 1] = T1 - pre1 - e1_0;
            sm.prep.z2pre[2 * t] = pre2;
            sm.prep.z2pre[2 * t + 1] = pre2 + e2_0;
            if (t == 0) { sm.prep.z1suf[512] = 0.f; sm.prep.z2pre[512] = T2; }
            __syncthreads();

            for (int rr = 0; rr < 2; ++rr) {
                int i = t + rr * 256;
                float d = dreg[rr];
                int lo = 0, hi = 512;
                while (lo < hi) {
                    int mid = (lo + hi) >> 1;
                    if (d + sm.prep.s_val[mid] >= 0.f) hi = mid; else lo = mid + 1;
                }
                int k = lo;
                float g = d + M;
                float Gv = (g >= 0.f) ? g : 0.2f * g;
                float al = __expf(g - Gv);
                float be = __expf(0.2f * g - Gv);
                float Z = al * sm.prep.z1suf[k] + be * sm.prep.z2pre[k];
                float inv = 1.0f / Z;
                g_aZ[bh * 512 + i] = al * inv;
                g_bZ[bh * 512 + i] = be * inv;
                g_k[bh * 512 + i]  = k;
            }
        }
        gridbar(release, arrive, ++bno, G);

        // ------------------------------------------------------------------
        // Phase C: attn_agg_fin (1024 virtual blocks)
        // ------------------------------------------------------------------
        for (int vb = blockIdx.x; vb < 1024; vb += G) {
            const int b  = vb & 63;
            const int cg = vb >> 6;        // 0..15
            const int c0 = cg * 4;
            const int lane = t & 63, wvw = t >> 6;
            const int cl = t & 3, ibase = t >> 2;  // cl: channel, ibase: seg 0..63

            float acc[8];
#pragma unroll
            for (int p = 0; p < 8; ++p) acc[p] = 0.f;

#pragma unroll 1
            for (int head = 0; head < 4; ++head) {
                const int bh = b * 4 + head;
                const float* hTb = hT + (size_t)(head * 64 + c0) * 32768 + b * 512;
                __syncthreads();   // prev head's (or prev phase's) reads done

                for (int rr = 0; rr < 2; ++rr) {
                    int r = t + rr * 256;
                    int j = g_sidx[bh * 512 + r];
                    float e1 = g_E1[bh * 512 + r];
                    float e2 = g_E2[bh * 512 + r];
                    sm.agg.kA[r]  = g_k[bh * 512 + r];
                    sm.agg.aZs[r] = g_aZ[bh * 512 + r];
                    sm.agg.bZs[r] = g_bZ[bh * 512 + r];
#pragma unroll
                    for (int c = 0; c < 4; ++c) {
                        float hvv = hTb[c * 32768 + j];
                        sm.agg.A1[c * APW + r] = e1 * hvv;
                        sm.agg.A2[c * APW + r] = e2 * hvv;
                    }
                }
                __syncthreads();

                float v1[8], v2[8];
                {
                    float* b1 = sm.agg.A1 + cl * APW + ibase * 8;
                    float* b2 = sm.agg.A2 + cl * APW + ibase * 8;
#pragma unroll
                    for (int q4 = 0; q4 < 2; ++q4) {
                        float4 a = *(const float4*)(b1 + q4 * 4);
                        v1[q4 * 4] = a.x; v1[q4 * 4 + 1] = a.y; v1[q4 * 4 + 2] = a.z; v1[q4 * 4 + 3] = a.w;
                        float4 c2 = *(const float4*)(b2 + q4 * 4);
                        v2[q4 * 4] = c2.x; v2[q4 * 4 + 1] = c2.y; v2[q4 * 4 + 2] = c2.z; v2[q4 * 4 + 3] = c2.w;
                    }
                    float s1 = 0.f, s2 = 0.f;
#pragma unroll
                    for (int i = 0; i < 8; ++i) { s1 += v1[i]; s2 += v2[i]; }
                    sm.agg.segs1[cl * 65 + ibase] = s1;
                    sm.agg.segs2[cl * 65 + ibase] = s2;
                }
                __syncthreads();

                {
                    float sv1 = sm.agg.segs1[wvw * 65 + lane];
                    float suf = sv1;
#pragma unroll
                    for (int off = 1; off < 64; off <<= 1) {
                        float u = __shfl_down(suf, off, 64);
                        if (lane + off < 64) suf += u;
                    }
                    sm.agg.segs1[wvw * 65 + lane] = suf - sv1;      // exclusive suffix
                    float sv2 = sm.agg.segs2[wvw * 65 + lane];
                    float pre = sv2;
#pragma unroll
                    for (int off = 1; off < 64; off <<= 1) {
                        float u = __shfl_up(pre, off, 64);
                        if (lane >= off) pre += u;
                    }
                    sm.agg.segs2[wvw * 65 + lane] = pre - sv2;      // exclusive prefix
                    if (lane == 63) sm.agg.tot[wvw] = pre;          // channel total
                }
                __syncthreads();

                {
                    float* b1 = sm.agg.A1 + cl * APW + ibase * 8;
                    float* b2 = sm.agg.A2 + cl * APW + ibase * 8;
                    float run = sm.agg.segs1[cl * 65 + ibase];
#pragma unroll
                    for (int i = 7; i >= 0; --i) { run += v1[i]; v1[i] = run; }      // incl suffix
                    float run2 = sm.agg.segs2[cl * 65 + ibase];
#pragma unroll
                    for (int i = 0; i < 8; ++i) { float tv = v2[i]; v2[i] = run2; run2 += tv; } // excl prefix
#pragma unroll
                    for (int q4 = 0; q4 < 2; ++q4) {
                        *(float4*)(b1 + q4 * 4) = make_float4(v1[q4 * 4], v1[q4 * 4 + 1],
                                                              v1[q4 * 4 + 2], v1[q4 * 4 + 3]);
                        *(float4*)(b2 + q4 * 4) = make_float4(v2[q4 * 4], v2[q4 * 4 + 1],
                                                              v2[q4 * 4 + 2], v2[q4 * 4 + 3]);
                    }
                }
                __syncthreads();

#pragma unroll
                for (int p = 0; p < 8; ++p) {
                    int i = p * 64 + ibase;
                    int k = sm.agg.kA[i];
                    float S1 = (k < 512) ? sm.agg.A1[cl * APW + k] : 0.f;
                    float P2 = (k < 512) ? sm.agg.A2[cl * APW + k] : sm.agg.tot[cl];
                    acc[p] += sm.agg.aZs[i] * S1 + sm.agg.bZs[i] * P2;
                }
            }

            const float bv = bias[c0 + cl];
#pragma unroll
            for (int p = 0; p < 8; ++p) {
                int i = p * 64 + ibase;
                xbuf[(size_t)(b * 512 + i) * 64 + c0 + cl] = fmaxf(0.25f * acc[p] + bv, 0.f);
            }
        }
        gridbar(release, arrive, ++bno, G);
    }

    // ----------------------------------------------------------------------
    // Phase D: readout (64 virtual blocks)
    // ----------------------------------------------------------------------
    for (int vb = blockIdx.x; vb < 64; vb += G) {
        const int b = vb;
        __syncthreads();              // union safety
        int c = t & 63, q = t >> 6;
        float acc = 0.f;
        for (int n = q; n < 512; n += 4) acc += xbuf[((size_t)b * 512 + n) * 64 + c];
        sm.ro.red[q][c] = acc;
        __syncthreads();
        if (t < 64) sm.ro.pooled[t] = (sm.ro.red[0][t] + sm.ro.red[1][t] +
                                       sm.ro.red[2][t] + sm.ro.red[3][t]) * (1.0f / 512.0f);
        __syncthreads();
        if (t < 64) {
            float a = rbv[t];
            for (int cc = 0; cc < 64; ++cc) a += sm.ro.pooled[cc] * rw[t * 64 + cc];
            out[b * 64 + t] = a;
        }
    }
}

extern "C" void kernel_launch(void* const* d_in, const int* in_sizes, int n_in,
                              void* d_out, int out_size, void* d_ws, size_t ws_size,
                              hipStream_t stream) {
    const float* emb       = (const float*)d_in[0];
    const float* lin_w     = (const float*)d_in[1];
    const float* att_src   = (const float*)d_in[2];
    const float* att_dst   = (const float*)d_in[3];
    const float* conv_b    = (const float*)d_in[4];
    const float* readout_w = (const float*)d_in[5];
    const float* readout_b = (const float*)d_in[6];

    float* ws  = (float*)d_ws;
    int*   bar = (int*)(ws + 12000000);    // release[16] + arrive[1024]

    // Co-residency-safe grid size from the compiled kernel's actual resource
    // usage (R16 trap fix: never launch more than guaranteed-resident).
    static int G = 0;
    if (G == 0) {
        int maxB = 0;
        if (hipOccupancyMaxActiveBlocksPerMultiprocessor(&maxB, mega_kernel, 256, 0) != hipSuccess || maxB < 1)
            maxB = 1;
        int dev = 0;
        hipGetDevice(&dev);
        int nCU = 0;
        if (hipDeviceGetAttribute(&nCU, hipDeviceAttributeMultiprocessorCount, dev) != hipSuccess || nCU < 1)
            nCU = 256;
        long cap = (long)maxB * (long)nCU;
        G = (int)(cap < 1024 ? cap : 1024);
        if (G < 1) G = 1;
    }

    // Zero release word(s) + per-block arrival flags (ws poisoned every iter).
    hipMemsetAsync(bar, 0, (16 + 1024) * sizeof(int), stream);
    mega_kernel<<<dim3(G), dim3(256), 0, stream>>>(emb, lin_w, att_src, att_dst,
                                                   conv_b, readout_w, readout_b,
                                                   (float*)d_out, ws);
}

// Round 4
// 265.514 us; speedup vs baseline: 2.9218x; 1.7348x over previous
//
#include <hip/hip_runtime.h>
#include <math.h>

// Problem constants (fixed by reference): B=64, N=512, D=64, H=4, C=64, L=3
// Workspace layout (floats), ws >= 256 MB:
//   xbuf [0 .. 2097152)         : layer activations x (8 MB)
//   hT   [2097152 .. 10485760)  : h TRANSPOSED [head][c][b*512+n] (32 MB)
//   meta [10485760 .. 11534336) : prep metadata + s/d dots (4 MB)
// History: R13 wave-shfl segs scans (295->266). R15 = 266 us known-good.
// R17-R19 persistent mega-kernel arc: 776 -> 615 -> 460 us (barrier cost
// mechanisms fixed one by one but floor stayed >> 265) -> arc TERMINATED
// per pre-committed decision rule; this is R15 restored.
// R20 change (ONE localized diff vs R15): agg's A-table fill previously did
// a random gather hT[..+g_sidx[r]] = 8.4M lane-divergent L1 messages per
// dispatch. Now prep emits E1/E2 indexed by ORIGINAL node id plus the
// INVERSE permutation g_rank (6 scattered stores/thread, a permutation so
// race-free); agg iterates original j (ALL global reads coalesced) and
// scatters into the rank-ordered LDS table (LDS scatter ~free). Bit-identical
// math. Decision rule: if >= 265 us, drop this diff and keep pure R15.

using short8  = __attribute__((ext_vector_type(8))) short;
using floatx4 = __attribute__((ext_vector_type(4))) float;

__device__ inline unsigned short f2bf(float f) {
    union { float f; unsigned u; } v; v.f = f;
    unsigned u = v.u + 0x7FFFu + ((v.u >> 16) & 1u);   // round-to-nearest-even
    return (unsigned short)(u >> 16);
}
__device__ inline float bf2f(unsigned short s) {
    union { float f; unsigned u; } v; v.u = ((unsigned)s) << 16;
    return v.f;
}

// ---------------------------------------------------------------------------
// Kernel A v8 (MFMA split-bf16, W staged ONCE, 4 x-tiles/block).
// ---------------------------------------------------------------------------
__global__ __launch_bounds__(256) void lin_kernel(const float* __restrict__ x,
                                                  const float* __restrict__ W,
                                                  const float* __restrict__ att_src,
                                                  const float* __restrict__ att_dst,
                                                  float* __restrict__ hT,
                                                  float* __restrict__ g_s,
                                                  float* __restrict__ g_d) {
    __shared__ unsigned short WH[64 * 72], WL[64 * 72];
    __shared__ unsigned short XH[16 * 72], XL[16 * 72];
    __shared__ float sredS[4][16], sredD[4][16];

    const int t = threadIdx.x;
    const int ct = blockIdx.x >> 9;       // head 0..3
    const int rb = blockIdx.x & 511;      // row-block (4 rt tiles)
    const int c0 = ct * 64;

#pragma unroll
    for (int q = 0; q < 4; ++q) {
        int f = q * 256 + t;
        int wrow = f >> 4, d4 = f & 15;
        float4 v = *(const float4*)(W + (size_t)(c0 + wrow) * 64 + d4 * 4);
        unsigned short h0 = f2bf(v.x), h1 = f2bf(v.y), h2 = f2bf(v.z), h3 = f2bf(v.w);
        ushort4 hi = make_ushort4(h0, h1, h2, h3);
        ushort4 lo = make_ushort4(f2bf(v.x - bf2f(h0)), f2bf(v.y - bf2f(h1)),
                                  f2bf(v.z - bf2f(h2)), f2bf(v.w - bf2f(h3)));
        *(ushort4*)&WH[wrow * 72 + d4 * 4] = hi;
        *(ushort4*)&WL[wrow * 72 + d4 * 4] = lo;
    }
    __syncthreads();

    const int lane = t & 63, wv = t >> 6;
    const int mrow = lane & 15, quad = lane >> 4;
    const int c = wv * 16 + mrow;

    short8 bh[2], bl[2];
#pragma unroll
    for (int kk = 0; kk < 2; ++kk) {
        int ko = kk * 32 + quad * 8;
        bh[kk] = *(const short8*)&WH[(wv * 16 + mrow) * 72 + ko];
        bl[kk] = *(const short8*)&WL[(wv * 16 + mrow) * 72 + ko];
    }
    const float as_c = att_src[c0 + c];
    const float ad_c = att_dst[c0 + c];

#pragma unroll 1
    for (int tt = 0; tt < 4; ++tt) {
        const int rt = rb * 4 + tt;
        const int r0 = rt * 16;
        __syncthreads();

        {
            int row = t >> 4, d4 = t & 15;
            float4 v = *(const float4*)(x + (size_t)(r0 + row) * 64 + d4 * 4);
            unsigned short h0 = f2bf(v.x), h1 = f2bf(v.y), h2 = f2bf(v.z), h3 = f2bf(v.w);
            ushort4 hi = make_ushort4(h0, h1, h2, h3);
            ushort4 lo = make_ushort4(f2bf(v.x - bf2f(h0)), f2bf(v.y - bf2f(h1)),
                                      f2bf(v.z - bf2f(h2)), f2bf(v.w - bf2f(h3)));
            *(ushort4*)&XH[row * 72 + d4 * 4] = hi;
            *(ushort4*)&XL[row * 72 + d4 * 4] = lo;
        }
        __syncthreads();

        short8 ah[2], al[2];
#pragma unroll
        for (int kk = 0; kk < 2; ++kk) {
            int ko = kk * 32 + quad * 8;
            ah[kk] = *(const short8*)&XH[mrow * 72 + ko];
            al[kk] = *(const short8*)&XL[mrow * 72 + ko];
        }

        floatx4 acc = {0.f, 0.f, 0.f, 0.f};
        acc = __builtin_amdgcn_mfma_f32_16x16x32_bf16(ah[0], bh[0], acc, 0, 0, 0);
        acc = __builtin_amdgcn_mfma_f32_16x16x32_bf16(ah[1], bh[1], acc, 0, 0, 0);
        acc = __builtin_amdgcn_mfma_f32_16x16x32_bf16(ah[0], bl[0], acc, 0, 0, 0);
        acc = __builtin_amdgcn_mfma_f32_16x16x32_bf16(ah[1], bl[1], acc, 0, 0, 0);
        acc = __builtin_amdgcn_mfma_f32_16x16x32_bf16(al[0], bh[0], acc, 0, 0, 0);
        acc = __builtin_amdgcn_mfma_f32_16x16x32_bf16(al[1], bh[1], acc, 0, 0, 0);

        *(float4*)&hT[(size_t)(ct * 64 + c) * 32768 + r0 + quad * 4] =
            make_float4(acc[0], acc[1], acc[2], acc[3]);

        float ps[4], pd[4];
#pragma unroll
        for (int reg = 0; reg < 4; ++reg) { ps[reg] = acc[reg] * as_c; pd[reg] = acc[reg] * ad_c; }
#pragma unroll
        for (int m = 1; m <= 8; m <<= 1) {
#pragma unroll
            for (int reg = 0; reg < 4; ++reg) {
                ps[reg] += __shfl_xor(ps[reg], m, 64);
                pd[reg] += __shfl_xor(pd[reg], m, 64);
            }
        }
        if (mrow < 4) {
            sredS[wv][quad * 4 + mrow] = ps[mrow];
            sredD[wv][quad * 4 + mrow] = pd[mrow];
        }
        __syncthreads();
        if (t < 16) {
            float sS = sredS[0][t] + sredS[1][t] + sredS[2][t] + sredS[3][t];
            float sD = sredD[0][t] + sredD[1][t] + sredD[2][t] + sredD[3][t];
            int gn = r0 + t;
            int bh2 = (gn >> 9) * 4 + ct;
            int n  = gn & 511;
            g_s[bh2 * 512 + n] = sS;
            g_d[bh2 * 512 + n] = sD;
        }
    }
}

// ---------------------------------------------------------------------------
// Kernel B1: attn_prep v4 — shuffle bitonic sort + wave scans.
// R20: outputs E1/E2 indexed by ORIGINAL node id + inverse permutation
// g_rank (rank of each original id in sorted order). id0/id1 form a
// permutation of 0..511 -> scattered stores are race-free.
// ---------------------------------------------------------------------------
__global__ __launch_bounds__(256) void attn_prep(const float* __restrict__ g_s,
                                                 const float* __restrict__ g_d,
                                                 int* __restrict__ g_rank,
                                                 float* __restrict__ g_E1,
                                                 float* __restrict__ g_E2,
                                                 float* __restrict__ g_aZ,
                                                 float* __restrict__ g_bZ,
                                                 int* __restrict__ g_k) {
    const int bh = blockIdx.x;
    const int t = threadIdx.x;
    const int lane = t & 63;
    const int wid = t >> 6;

    __shared__ float s_val[512];
    __shared__ int   s_idxE[512];
    __shared__ float z1suf[513], z2pre[513];
    __shared__ float wred[8];

    float dreg[2];
    for (int rr = 0; rr < 2; ++rr) {
        int j = t + rr * 256;
        s_val[j] = g_s[bh * 512 + j];
        dreg[rr] = g_d[bh * 512 + j];
    }
    __syncthreads();

    float v0 = s_val[2 * t], v1 = s_val[2 * t + 1];
    int id0 = 2 * t, id1 = 2 * t + 1;
    for (int k = 2; k <= 512; k <<= 1) {
        for (int j = k >> 1; j >= 1; j >>= 1) {
            bool asc = ((t & (k >> 1)) == 0);
            if (j == 1) {
                bool sw = asc ? (v0 > v1) : (v0 < v1);
                if (sw) { float tv = v0; v0 = v1; v1 = tv; int ti = id0; id0 = id1; id1 = ti; }
            } else if (j <= 64) {
                int m = j >> 1;
                float w0 = __shfl_xor(v0, m, 64);
                int  wi0 = __shfl_xor(id0, m, 64);
                float w1 = __shfl_xor(v1, m, 64);
                int  wi1 = __shfl_xor(id1, m, 64);
                bool low = ((t & m) == 0);
                bool wantmin = (low == asc);
                if (wantmin ? (w0 < v0) : (w0 > v0)) { v0 = w0; id0 = wi0; }
                if (wantmin ? (w1 < v1) : (w1 > v1)) { v1 = w1; id1 = wi1; }
            } else {
                int m = j >> 1;
                s_val[2 * t] = v0; s_val[2 * t + 1] = v1;
                s_idxE[2 * t] = id0; s_idxE[2 * t + 1] = id1;
                __syncthreads();
                int tp = t ^ m;
                float w0 = s_val[2 * tp], w1 = s_val[2 * tp + 1];
                int wi0 = s_idxE[2 * tp], wi1 = s_idxE[2 * tp + 1];
                bool low = ((t & m) == 0);
                bool wantmin = (low == asc);
                if (wantmin ? (w0 < v0) : (w0 > v0)) { v0 = w0; id0 = wi0; }
                if (wantmin ? (w1 < v1) : (w1 > v1)) { v1 = w1; id1 = wi1; }
                __syncthreads();
            }
        }
    }

    s_val[2 * t] = v0; s_val[2 * t + 1] = v1;
    __syncthreads();
    const float M = s_val[511];
    float e1_0 = __expf(v0 - M), e1_1 = __expf(v1 - M);
    float e2_0 = __expf(0.2f * (v0 - M)), e2_1 = __expf(0.2f * (v1 - M));
    // R20: scatter by original id (permutation -> race-free), store inverse rank.
    {
        const int base = bh * 512;
        g_E1[base + id0] = e1_0;  g_E1[base + id1] = e1_1;
        g_E2[base + id0] = e2_0;  g_E2[base + id1] = e2_1;
        g_rank[base + id0] = 2 * t;  g_rank[base + id1] = 2 * t + 1;
    }

    float S1 = e1_0 + e1_1, S2 = e2_0 + e2_1;
    float i1 = S1, i2 = S2;
    for (int off = 1; off < 64; off <<= 1) {
        float u1 = __shfl_up(i1, off, 64);
        float u2 = __shfl_up(i2, off, 64);
        if (lane >= off) { i1 += u1; i2 += u2; }
    }
    if (lane == 63) { wred[wid] = i1; wred[4 + wid] = i2; }
    __syncthreads();
    float off1 = 0.f, off2 = 0.f;
    for (int w = 0; w < wid; ++w) { off1 += wred[w]; off2 += wred[4 + w]; }
    const float T1 = wred[0] + wred[1] + wred[2] + wred[3];
    const float T2 = wred[4] + wred[5] + wred[6] + wred[7];
    float pre1 = off1 + i1 - S1;
    float pre2 = off2 + i2 - S2;
    z1suf[2 * t] = T1 - pre1;
    z1suf[2 * t + 1] = T1 - pre1 - e1_0;
    z2pre[2 * t] = pre2;
    z2pre[2 * t + 1] = pre2 + e2_0;
    if (t == 0) { z1suf[512] = 0.f; z2pre[512] = T2; }
    __syncthreads();

    for (int rr = 0; rr < 2; ++rr) {
        int i = t + rr * 256;
        float d = dreg[rr];
        int lo = 0, hi = 512;
        while (lo < hi) {
            int mid = (lo + hi) >> 1;
            if (d + s_val[mid] >= 0.f) hi = mid; else lo = mid + 1;
        }
        int k = lo;
        float g = d + M;
        float G = (g >= 0.f) ? g : 0.2f * g;
        float al = __expf(g - G);
        float be = __expf(0.2f * g - G);
        float Z = al * z1suf[k] + be * z2pre[k];
        float inv = 1.0f / Z;
        g_aZ[bh * 512 + i] = al * inv;
        g_bZ[bh * 512 + i] = be * inv;
        g_k[bh * 512 + i]  = k;
    }
}

// ---------------------------------------------------------------------------
// Kernel B2: attn_agg_fin v6 — R20: A-table fill iterates ORIGINAL j
// (every global read coalesced: rank/E1/E2/k/aZ/bZ/hT) and scatters into
// the rank-ordered LDS tables (replaces 8.4M random hT gathers/dispatch).
// Scan + query machinery unchanged -> bit-identical results.
// ---------------------------------------------------------------------------
#define APW 516
__global__ __launch_bounds__(256) void attn_agg_fin(const float* __restrict__ hT,
                                                    const int* __restrict__ g_rank,
                                                    const float* __restrict__ g_E1,
                                                    const float* __restrict__ g_E2,
                                                    const float* __restrict__ g_aZ,
                                                    const float* __restrict__ g_bZ,
                                                    const int* __restrict__ g_k,
                                                    const float* __restrict__ bias,
                                                    float* __restrict__ x) {
    const int b  = blockIdx.x & 63;
    const int cg = blockIdx.x >> 6;        // 0..15
    const int c0 = cg * 4;
    const int t = threadIdx.x;
    const int lane = t & 63, wvw = t >> 6;

    __shared__ float A1[4 * APW], A2[4 * APW];
    __shared__ float segs1[4 * 65], segs2[4 * 65];
    __shared__ float tot[4];
    __shared__ int   kA[512];
    __shared__ float aZs[512], bZs[512];

    const int cl = t & 3, ibase = t >> 2;  // cl: channel, ibase: seg 0..63
    float acc[8];
#pragma unroll
    for (int p = 0; p < 8; ++p) acc[p] = 0.f;

#pragma unroll 1
    for (int head = 0; head < 4; ++head) {
        const int bh = b * 4 + head;
        const float* hTb = hT + (size_t)(head * 64 + c0) * 32768 + b * 512;
        __syncthreads();   // prev head's queries done before table overwrite

        // Fill BOTH tables: coalesced reads, LDS scatter by inverse rank.
        for (int rr = 0; rr < 2; ++rr) {
            int j = t + rr * 256;                  // ORIGINAL node index
            int rk = g_rank[bh * 512 + j];         // rank in sorted order
            float e1 = g_E1[bh * 512 + j];
            float e2 = g_E2[bh * 512 + j];
            kA[j]  = g_k[bh * 512 + j];
            aZs[j] = g_aZ[bh * 512 + j];
            bZs[j] = g_bZ[bh * 512 + j];
#pragma unroll
            for (int c = 0; c < 4; ++c) {
                float hvv = hTb[c * 32768 + j];    // coalesced (j sequential)
                A1[c * APW + rk] = e1 * hvv;       // LDS scatter
                A2[c * APW + rk] = e2 * hvv;
            }
        }
        __syncthreads();

        // Thread-local segment sums for both tables (8 rows each)
        float v1[8], v2[8];
        {
            float* b1 = A1 + cl * APW + ibase * 8;
            float* b2 = A2 + cl * APW + ibase * 8;
#pragma unroll
            for (int q4 = 0; q4 < 2; ++q4) {
                float4 a = *(const float4*)(b1 + q4 * 4);
                v1[q4 * 4] = a.x; v1[q4 * 4 + 1] = a.y; v1[q4 * 4 + 2] = a.z; v1[q4 * 4 + 3] = a.w;
                float4 c2 = *(const float4*)(b2 + q4 * 4);
                v2[q4 * 4] = c2.x; v2[q4 * 4 + 1] = c2.y; v2[q4 * 4 + 2] = c2.z; v2[q4 * 4 + 3] = c2.w;
            }
            float s1 = 0.f, s2 = 0.f;
#pragma unroll
            for (int i = 0; i < 8; ++i) { s1 += v1[i]; s2 += v2[i]; }
            segs1[cl * 65 + ibase] = s1;
            segs2[cl * 65 + ibase] = s2;
        }
        __syncthreads();

        // Wave wvw scans channel wvw's segs: suffix on segs1, prefix on segs2
        {
            float sv1 = segs1[wvw * 65 + lane];
            float suf = sv1;
#pragma unroll
            for (int off = 1; off < 64; off <<= 1) {
                float u = __shfl_down(suf, off, 64);
                if (lane + off < 64) suf += u;
            }
            segs1[wvw * 65 + lane] = suf - sv1;      // exclusive suffix
            float sv2 = segs2[wvw * 65 + lane];
            float pre = sv2;
#pragma unroll
            for (int off = 1; off < 64; off <<= 1) {
                float u = __shfl_up(pre, off, 64);
                if (lane >= off) pre += u;
            }
            segs2[wvw * 65 + lane] = pre - sv2;      // exclusive prefix
            if (lane == 63) tot[wvw] = pre;          // channel total
        }
        __syncthreads();

        // Write back scanned tables (both)
        {
            float* b1 = A1 + cl * APW + ibase * 8;
            float* b2 = A2 + cl * APW + ibase * 8;
            float run = segs1[cl * 65 + ibase];
#pragma unroll
            for (int i = 7; i >= 0; --i) { run += v1[i]; v1[i] = run; }      // incl suffix
            float run2 = segs2[cl * 65 + ibase];
#pragma unroll
            for (int i = 0; i < 8; ++i) { float tv = v2[i]; v2[i] = run2; run2 += tv; } // excl prefix
#pragma unroll
            for (int q4 = 0; q4 < 2; ++q4) {
                *(float4*)(b1 + q4 * 4) = make_float4(v1[q4 * 4], v1[q4 * 4 + 1],
                                                      v1[q4 * 4 + 2], v1[q4 * 4 + 3]);
                *(float4*)(b2 + q4 * 4) = make_float4(v2[q4 * 4], v2[q4 * 4 + 1],
                                                      v2[q4 * 4 + 2], v2[q4 * 4 + 3]);
            }
        }
        __syncthreads();

        // Queries (both tables at once)
#pragma unroll
        for (int p = 0; p < 8; ++p) {
            int i = p * 64 + ibase;
            int k = kA[i];
            float S1 = (k < 512) ? A1[cl * APW + k] : 0.f;
            float P2 = (k < 512) ? A2[cl * APW + k] : tot[cl];
            acc[p] += aZs[i] * S1 + bZs[i] * P2;
        }
    }

    // Finalize fused: x = relu(mean_heads + bias), fp32 coalesced
    const float bv = bias[c0 + cl];
#pragma unroll
    for (int p = 0; p < 8; ++p) {
        int i = p * 64 + ibase;
        x[(size_t)(b * 512 + i) * 64 + c0 + cl] = fmaxf(0.25f * acc[p] + bv, 0.f);
    }
}

// ---------------------------------------------------------------------------
// Kernel D: out[b][d] = (mean_n x[b][n][:]) . readout_w[d][:] + readout_b[d]
// ---------------------------------------------------------------------------
__global__ __launch_bounds__(256) void readout_kernel(const float* __restrict__ x,
                                                      const float* __restrict__ rw,
                                                      const float* __restrict__ rb,
                                                      float* __restrict__ out) {
    __shared__ float red[4][64];
    __shared__ float pooled[64];
    int b = blockIdx.x, t = threadIdx.x;
    int c = t & 63, q = t >> 6;
    float acc = 0.f;
    for (int n = q; n < 512; n += 4) acc += x[((size_t)b * 512 + n) * 64 + c];
    red[q][c] = acc;
    __syncthreads();
    if (t < 64) pooled[t] = (red[0][t] + red[1][t] + red[2][t] + red[3][t]) * (1.0f / 512.0f);
    __syncthreads();
    if (t < 64) {
        float a = rb[t];
        for (int cc = 0; cc < 64; ++cc) a += pooled[cc] * rw[t * 64 + cc];
        out[b * 64 + t] = a;
    }
}

extern "C" void kernel_launch(void* const* d_in, const int* in_sizes, int n_in,
                              void* d_out, int out_size, void* d_ws, size_t ws_size,
                              hipStream_t stream) {
    const float* emb       = (const float*)d_in[0];
    const float* lin_w     = (const float*)d_in[1];
    const float* att_src   = (const float*)d_in[2];
    const float* att_dst   = (const float*)d_in[3];
    const float* conv_b    = (const float*)d_in[4];
    const float* readout_w = (const float*)d_in[5];
    const float* readout_b = (const float*)d_in[6];
    float* out = (float*)d_out;

    float* ws   = (float*)d_ws;
    float* xbuf = ws;                    // 8 MB
    float* hT   = ws + 2097152;          // 32 MB, [head][c][b*512+n]
    float* meta = ws + 10485760;         // 4 MB

    int*   g_rank = (int*)meta;          // (was g_sidx; now inverse rank)
    float* g_E1   = meta + 131072;       // indexed by ORIGINAL id (R20)
    float* g_E2   = meta + 262144;       // indexed by ORIGINAL id (R20)
    float* g_aZ   = meta + 393216;
    float* g_bZ   = meta + 524288;
    int*   g_k    = (int*)(meta + 655360);
    float* g_s    = meta + 786432;
    float* g_d    = meta + 917504;

    for (int l = 0; l < 3; ++l) {
        const float* xin = (l == 0) ? emb : xbuf;
        lin_kernel<<<2048, 256, 0, stream>>>(xin, lin_w + (size_t)l * 16384,
                                             att_src + l * 256, att_dst + l * 256,
                                             hT, g_s, g_d);
        attn_prep<<<256, 256, 0, stream>>>(g_s, g_d,
                                           g_rank, g_E1, g_E2, g_aZ, g_bZ, g_k);
        attn_agg_fin<<<1024, 256, 0, stream>>>(hT, g_rank, g_E1, g_E2, g_aZ, g_bZ, g_k,
                                               conv_b + l * 64, xbuf);
    }
    readout_kernel<<<64, 256, 0, stream>>>(xbuf, readout_w, readout_b, out);
}